// Round 1
// baseline (521.074 us; speedup 1.0000x reference)
//
#include <hip/hip_runtime.h>
#include <cstdint>
#include <cstddef>

#define B_   8
#define E_   16
#define CIN_ 64
#define C_   64
#define HW_  4096

typedef __attribute__((ext_vector_type(8))) short short8;
typedef __attribute__((ext_vector_type(4))) float floatx4;

// selu(x) = scale*x (x>0) ; scale*alpha*(exp(x)-1) (x<=0)
__device__ __forceinline__ float selu_f(float v) {
    const float kAlphaScale = 1.7580993408473766f;  // alpha*scale
    const float kScale      = 1.0507009873554805f;
    return v > 0.0f ? kScale * v : kAlphaScale * (__expf(v) - 1.0f);
}

__device__ __forceinline__ unsigned short f2bf(float f) {
    unsigned int u = __float_as_uint(f);
    u += 0x7fffu + ((u >> 16) & 1u);   // RNE
    return (unsigned short)(u >> 16);
}
__device__ __forceinline__ float bf2f(unsigned short h) {
    return __uint_as_float(((unsigned int)h) << 16);
}

// ---------- W staging, XOR-swizzled [64][64] bf16 (no pad; k ^= (row&7)<<3) ----------
// b128 frag reads are 8-aligned in k, swizzle value is a multiple of 8 -> contiguity
// of each 8-element fragment is preserved: (k0+j)^s == (k0^s)+j for j<8.
__device__ __forceinline__ void stage_w_sw(const float* __restrict__ W,
                                           unsigned short* Wh, unsigned short* Wl, int t) {
    for (int idx = t; idx < 4096; idx += 256) {
        const int c = idx >> 6, k = idx & 63;
        const int o = c * 64 + (k ^ ((c & 7) << 3));
        const float f = W[idx];
        const unsigned short h = f2bf(f);
        Wh[o] = h;
        Wl[o] = f2bf(f - bf2f(h));
    }
}
__device__ __forceinline__ void stage_w_hi(const float* __restrict__ W,
                                           unsigned short* Wh, int t) {
    for (int idx = t; idx < 4096; idx += 256) {
        const int c = idx >> 6, k = idx & 63;
        Wh[c * 64 + (k ^ ((c & 7) << 3))] = f2bf(W[idx]);
    }
}

// legacy padded staging (fallback out_kernel only)
#define WPAD 72
__device__ __forceinline__ void stage_w(const float* __restrict__ W,
                                        unsigned short* Wh, unsigned short* Wl, int t) {
    for (int idx = t; idx < 4096; idx += 256) {
        const int c = idx >> 6, k = idx & 63;
        const float f = W[idx];
        const unsigned short h = f2bf(f);
        Wh[c * WPAD + k] = h;
        Wl[c * WPAD + k] = f2bf(f - bf2f(h));
    }
}

// ---------------- kernel 1: K/Q conv (MFMA) + gram partials + fused V conv ----------------
// grid 512 (= B*64 px-tiles of 64), block 256 (4 waves).
// Wave w convs members 4w..4w+3 via mfma_f32_16x16x32_bf16 with hi/lo split;
// gram over members stays fp32 VALU. V conv (2-term: Wh*xh + Wh*xl) reuses the
// in-register x fragments and streams bf16 V to global (read back by combine_kernel).
#define K1_CH 4
#define KCS 18    // sK c-stride (16 px padded to 18)
#define KIS 292   // sK member-stride (16*18+4)

__global__ __launch_bounds__(256, 2)
void dots_kernel(const float* __restrict__ x,
                 const float* __restrict__ Wk, const float* __restrict__ bk,
                 const float* __restrict__ Wq, const float* __restrict__ bq,
                 const float* __restrict__ Wv, const float* __restrict__ bv,
                 unsigned short* __restrict__ vbuf,   // may be null (no V fusion)
                 float* __restrict__ wts, float* __restrict__ part,
                 int use_atomic)
{
    __shared__ float sK[E_ * KIS];
    __shared__ float sQ[E_ * KIS];
    __shared__ __align__(16) unsigned short Wkh[4096], Wkl[4096];
    __shared__ __align__(16) unsigned short Wqh[4096], Wql[4096];
    __shared__ __align__(16) unsigned short Wvh[4096];

    const int t    = threadIdx.x;
    const int b    = blockIdx.x >> 6;
    const int blk  = blockIdx.x & 63;
    const int wv   = t >> 6;          // wave id: members 4wv..4wv+3
    const int lane = t & 63;
    const int quad = lane >> 4;
    const int pxl  = lane & 15;       // B-frag n / D col
    const int m16  = lane & 15;       // A-frag m
    // gram mapping (block-wide)
    const int gc = t >> 4;            // channel-in-quarter
    const int s  = t & 15;
    const int ib = (s >> 2) << 2;
    const int jb = (s & 3) << 2;

    stage_w_sw(Wk, Wkh, Wkl, t);
    stage_w_sw(Wq, Wqh, Wql, t);
    if (vbuf) stage_w_hi(Wv, Wvh, t);

    float acc[4][4][4];
    #pragma unroll
    for (int a0 = 0; a0 < 4; ++a0)
      #pragma unroll
      for (int a1 = 0; a1 < 4; ++a1)
        #pragma unroll
        for (int a2 = 0; a2 < 4; ++a2) acc[a0][a1][a2] = 0.0f;

    __syncthreads();   // W staged

    for (int chunk = 0; chunk < K1_CH; ++chunk) {
        const int p0 = blk * (16 * K1_CH) + chunk * 16;

        // x B-frags: lane holds x[cin=kk*32+quad*8+j][px=p0+pxl], hi/lo bf16
        short8 xh[4][2], xl[4][2];
        #pragma unroll
        for (int mi = 0; mi < 4; ++mi) {
            const int im = 4 * wv + mi;
            const float* xg = x + ((size_t)(b * E_ + im) * CIN_) * HW_ + p0 + pxl;
            #pragma unroll
            for (int kk = 0; kk < 2; ++kk) {
                float xv[8];
                #pragma unroll
                for (int j = 0; j < 8; ++j)
                    xv[j] = xg[(size_t)(kk * 32 + quad * 8 + j) * HW_];
                #pragma unroll
                for (int j = 0; j < 8; ++j) {
                    const unsigned short h = f2bf(xv[j]);
                    xh[mi][kk][j] = (short)h;
                    xl[mi][kk][j] = (short)f2bf(xv[j] - bf2f(h));
                }
            }
        }

        for (int q4 = 0; q4 < 4; ++q4) {
            const int row = q4 * 16 + m16;
            const int ksw = (row & 7) << 3;

            // ---- V conv first (global stores issue early, hidden under K/Q conv) ----
            if (vbuf) {
                short8 vh[2];
                #pragma unroll
                for (int kk = 0; kk < 2; ++kk) {
                    const int k0 = kk * 32 + quad * 8;
                    vh[kk] = *(const short8*)&Wvh[row * 64 + (k0 ^ ksw)];
                }
                float bvv[4];
                #pragma unroll
                for (int r = 0; r < 4; ++r) bvv[r] = bv[q4 * 16 + quad * 4 + r];
                #pragma unroll
                for (int mi = 0; mi < 4; ++mi) {
                    floatx4 d = {0.f, 0.f, 0.f, 0.f};
                    d = __builtin_amdgcn_mfma_f32_16x16x32_bf16(vh[0], xh[mi][0], d, 0, 0, 0);
                    d = __builtin_amdgcn_mfma_f32_16x16x32_bf16(vh[0], xl[mi][0], d, 0, 0, 0);
                    d = __builtin_amdgcn_mfma_f32_16x16x32_bf16(vh[1], xh[mi][1], d, 0, 0, 0);
                    d = __builtin_amdgcn_mfma_f32_16x16x32_bf16(vh[1], xl[mi][1], d, 0, 0, 0);
                    const int im = 4 * wv + mi;
                    #pragma unroll
                    for (int r = 0; r < 4; ++r)
                        vbuf[((size_t)(b * E_ + im) * C_ + (q4 * 16 + quad * 4 + r)) * HW_ + p0 + pxl]
                            = f2bf(d[r] + bvv[r]);
                }
            }

            // ---- K conv for this channel quarter ----
            {
                short8 ah[2], al[2];
                #pragma unroll
                for (int kk = 0; kk < 2; ++kk) {
                    const int k0 = kk * 32 + quad * 8;
                    const int off = row * 64 + (k0 ^ ksw);
                    ah[kk] = *(const short8*)&Wkh[off];
                    al[kk] = *(const short8*)&Wkl[off];
                }
                float bkv[4];
                #pragma unroll
                for (int r = 0; r < 4; ++r) bkv[r] = bk[q4 * 16 + quad * 4 + r];
                #pragma unroll
                for (int mi = 0; mi < 4; ++mi) {
                    floatx4 d = {0.f, 0.f, 0.f, 0.f};
                    #pragma unroll
                    for (int kk = 0; kk < 2; ++kk) {
                        d = __builtin_amdgcn_mfma_f32_16x16x32_bf16(ah[kk], xh[mi][kk], d, 0, 0, 0);
                        d = __builtin_amdgcn_mfma_f32_16x16x32_bf16(ah[kk], xl[mi][kk], d, 0, 0, 0);
                        d = __builtin_amdgcn_mfma_f32_16x16x32_bf16(al[kk], xh[mi][kk], d, 0, 0, 0);
                    }
                    const int im = 4 * wv + mi;
                    #pragma unroll
                    for (int r = 0; r < 4; ++r)
                        sK[im * KIS + (quad * 4 + r) * KCS + pxl] = selu_f(d[r] + bkv[r]);
                }
            }
            // ---- Q conv for this channel quarter ----
            {
                short8 ah[2], al[2];
                #pragma unroll
                for (int kk = 0; kk < 2; ++kk) {
                    const int k0 = kk * 32 + quad * 8;
                    const int off = row * 64 + (k0 ^ ksw);
                    ah[kk] = *(const short8*)&Wqh[off];
                    al[kk] = *(const short8*)&Wql[off];
                }
                float bqv[4];
                #pragma unroll
                for (int r = 0; r < 4; ++r) bqv[r] = bq[q4 * 16 + quad * 4 + r];
                #pragma unroll
                for (int mi = 0; mi < 4; ++mi) {
                    floatx4 d = {0.f, 0.f, 0.f, 0.f};
                    #pragma unroll
                    for (int kk = 0; kk < 2; ++kk) {
                        d = __builtin_amdgcn_mfma_f32_16x16x32_bf16(ah[kk], xh[mi][kk], d, 0, 0, 0);
                        d = __builtin_amdgcn_mfma_f32_16x16x32_bf16(ah[kk], xl[mi][kk], d, 0, 0, 0);
                        d = __builtin_amdgcn_mfma_f32_16x16x32_bf16(al[kk], xh[mi][kk], d, 0, 0, 0);
                    }
                    const int im = 4 * wv + mi;
                    #pragma unroll
                    for (int r = 0; r < 4; ++r)
                        sQ[im * KIS + (quad * 4 + r) * KCS + pxl] = selu_f(d[r] + bqv[r]);
                }
            }
            __syncthreads();
            // ---- gram: dots[c=q4*16+gc][i=ib+u][j=jb+v] += K_i*Q_j over 16 px ----
            #pragma unroll
            for (int p2 = 0; p2 < 8; ++p2) {
                float2 kv[4], qv[4];
                #pragma unroll
                for (int u = 0; u < 4; ++u)
                    kv[u] = *(const float2*)&sK[(ib + u) * KIS + gc * KCS + 2 * p2];
                #pragma unroll
                for (int v = 0; v < 4; ++v)
                    qv[v] = *(const float2*)&sQ[(jb + v) * KIS + gc * KCS + 2 * p2];
                #pragma unroll
                for (int u = 0; u < 4; ++u)
                    #pragma unroll
                    for (int v = 0; v < 4; ++v)
                        acc[q4][u][v] = __fmaf_rn(kv[u].y, qv[v].y,
                                         __fmaf_rn(kv[u].x, qv[v].x, acc[q4][u][v]));
            }
            __syncthreads();
        }
    }

    if (use_atomic) {
        #pragma unroll
        for (int q4 = 0; q4 < 4; ++q4)
          #pragma unroll
          for (int u = 0; u < 4; ++u)
            #pragma unroll
            for (int v = 0; v < 4; ++v)
              atomicAdd(&wts[(((size_t)b * C_ + (q4 * 16 + gc)) * E_ + (ib + u)) * E_ + (jb + v)],
                        acc[q4][u][v]);
    } else {
        float* pb = part + (size_t)blockIdx.x * (C_ * E_ * E_);
        #pragma unroll
        for (int q4 = 0; q4 < 4; ++q4) {
            __syncthreads();
            #pragma unroll
            for (int u = 0; u < 4; ++u)
              #pragma unroll
              for (int v = 0; v < 4; ++v)
                sK[gc * 256 + (ib + u) * 16 + (jb + v)] = acc[q4][u][v];
            __syncthreads();
            for (int e = t; e < 4096; e += 256)
                pb[q4 * 4096 + e] = sK[e];
        }
    }
}

// ---------------- kernel 2a: reduce partials ----------------
__global__ __launch_bounds__(256)
void reduce_kernel(const float* __restrict__ part, float* __restrict__ wts)
{
    const int tid = blockIdx.x * 256 + threadIdx.x;  // 0..32767 float4 slots
    const int b   = tid >> 12;
    const int off = tid & 4095;
    float4 sum = make_float4(0.f, 0.f, 0.f, 0.f);
    const float* base = part + (size_t)b * 64 * 16384;
    #pragma unroll 8
    for (int blk = 0; blk < 64; ++blk) {
        float4 v = *(const float4*)(base + (size_t)blk * 16384 + off * 4);
        sum.x += v.x; sum.y += v.y; sum.z += v.z; sum.w += v.w;
    }
    *(float4*)(wts + (size_t)b * 16384 + off * 4) = sum;
}

// ---------------- kernel 2b: softmax over i ----------------
__global__ __launch_bounds__(256)
void softmax_kernel(float* __restrict__ wts)
{
    const int tid = blockIdx.x * 256 + threadIdx.x;  // 8192 = B*C*E(j)
    const int j   = tid & 15;
    const int bc  = tid >> 4;
    float* base = wts + (size_t)bc * 256 + j;
    float v[16];
    #pragma unroll
    for (int i = 0; i < 16; ++i) v[i] = base[i * 16];
    float m = v[0];
    #pragma unroll
    for (int i = 1; i < 16; ++i) m = fmaxf(m, v[i]);
    float sum = 0.f;
    #pragma unroll
    for (int i = 0; i < 16; ++i) { v[i] = __expf(v[i] - m); sum += v[i]; }
    const float r = 1.0f / sum;
    #pragma unroll
    for (int i = 0; i < 16; ++i) base[i * 16] = v[i] * r;
}

// ---------------- kernel 3 (fused path): streaming combine from precomputed V ----------------
// grid 512 (= B*64 tiles of 64 px), block 256, 4 chunks of 16 px.
// out[b,j,c,p] = selu( sum_i w[b,c,i,j] * V[b,i,c,p] )   (mean cancels: sum_i w = 1)
#define VCS 20      // sV c-stride (ushort; mult of 4 for aligned uint2 reads)
#define VIS 1284    // sV member-stride (64*20+4)

__global__ __launch_bounds__(256, 2)
void combine_kernel(const unsigned short* __restrict__ vbuf,
                    const float* __restrict__ wts, float* __restrict__ out)
{
    __shared__ __align__(16) unsigned short sV[E_ * VIS];

    const int t   = threadIdx.x;
    const int b   = blockIdx.x >> 6;
    const int blk = blockIdx.x & 63;
    const int c   = t >> 2;     // combine: channel
    const int q   = t & 3;      // combine: j-quad

    for (int chunk = 0; chunk < 4; ++chunk) {
        const int p0 = blk * 64 + chunk * 16;

        if (chunk) __syncthreads();    // previous chunk's sV reads complete
        // stage V chunk: 16 i x 64 c x 16 px bf16 = 32 KB
        for (int idx = t; idx < 2048; idx += 256) {
            const int i    = idx >> 7;
            const int rest = idx & 127;
            const int cc   = rest >> 1;
            const int h    = rest & 1;
            const uint4 u = *(const uint4*)(vbuf +
                (((size_t)(b * E_ + i) * C_ + cc) * HW_ + p0 + h * 8));
            unsigned short* dst = &sV[i * VIS + cc * VCS + h * 8];
            *(uint2*)dst       = make_uint2(u.x, u.y);
            *(uint2*)(dst + 4) = make_uint2(u.z, u.w);
        }
        __syncthreads();

        float acc2[4][16];
        #pragma unroll
        for (int jj = 0; jj < 4; ++jj)
            #pragma unroll
            for (int pp = 0; pp < 16; ++pp) acc2[jj][pp] = 0.f;

        #pragma unroll 4
        for (int i2 = 0; i2 < 16; ++i2) {
            const float4 w4 = *(const float4*)&wts[(((size_t)b * C_ + c) * E_ + i2) * E_ + 4 * q];
            const unsigned short* vp = &sV[i2 * VIS + c * VCS];
            float vvv[16];
            #pragma unroll
            for (int pq = 0; pq < 4; ++pq) {
                const uint2 u = *(const uint2*)(vp + 4 * pq);
                vvv[4 * pq + 0] = __uint_as_float(u.x << 16);
                vvv[4 * pq + 1] = __uint_as_float(u.x & 0xffff0000u);
                vvv[4 * pq + 2] = __uint_as_float(u.y << 16);
                vvv[4 * pq + 3] = __uint_as_float(u.y & 0xffff0000u);
            }
            const float wj0 = w4.x, wj1 = w4.y, wj2 = w4.z, wj3 = w4.w;
            #pragma unroll
            for (int pp = 0; pp < 16; ++pp) {
                acc2[0][pp] = __fmaf_rn(wj0, vvv[pp], acc2[0][pp]);
                acc2[1][pp] = __fmaf_rn(wj1, vvv[pp], acc2[1][pp]);
                acc2[2][pp] = __fmaf_rn(wj2, vvv[pp], acc2[2][pp]);
                acc2[3][pp] = __fmaf_rn(wj3, vvv[pp], acc2[3][pp]);
            }
        }

        #pragma unroll
        for (int jj = 0; jj < 4; ++jj) {
            const int j = 4 * q + jj;
            float* op = out + ((size_t)((b * E_ + j) * C_ + c)) * HW_ + p0;
            #pragma unroll
            for (int pq = 0; pq < 4; ++pq) {
                float4 o;
                o.x = selu_f(acc2[jj][4 * pq + 0]);
                o.y = selu_f(acc2[jj][4 * pq + 1]);
                o.z = selu_f(acc2[jj][4 * pq + 2]);
                o.w = selu_f(acc2[jj][4 * pq + 3]);
                *(float4*)(op + 4 * pq) = o;
            }
        }
    }
}

// ---------------- kernel 3 (fallback): V conv (MFMA) + combine + selu ----------------
// Used only when workspace can't hold the V buffer. Unchanged verified code.
#define K3_CH 2

__global__ __launch_bounds__(256, 2)
void out_kernel(const float* __restrict__ x,
                const float* __restrict__ Wv, const float* __restrict__ bv,
                const float* __restrict__ wts, float* __restrict__ out)
{
    __shared__ __align__(16) unsigned short sV[E_ * VIS];   // V staged bf16
    __shared__ __align__(16) unsigned short Wvh[64 * WPAD], Wvl[64 * WPAD];

    const int t    = threadIdx.x;
    const int b    = blockIdx.x >> 7;
    const int blk  = blockIdx.x & 127;
    const int wv   = t >> 6;
    const int lane = t & 63;
    const int quad = lane >> 4;
    const int pxl  = lane & 15;
    const int m16  = lane & 15;
    const int c    = t >> 2;     // combine: channel
    const int q    = t & 3;      // combine: j-quad

    stage_w(Wv, Wvh, Wvl, t);
    __syncthreads();

    for (int chunk = 0; chunk < K3_CH; ++chunk) {
        const int p0 = blk * (16 * K3_CH) + chunk * 16;

        short8 xh[4][2], xl[4][2];
        #pragma unroll
        for (int mi = 0; mi < 4; ++mi) {
            const int im = 4 * wv + mi;
            const float* xg = x + ((size_t)(b * E_ + im) * CIN_) * HW_ + p0 + pxl;
            #pragma unroll
            for (int kk = 0; kk < 2; ++kk) {
                float xv[8];
                #pragma unroll
                for (int j = 0; j < 8; ++j)
                    xv[j] = xg[(size_t)(kk * 32 + quad * 8 + j) * HW_];
                #pragma unroll
                for (int j = 0; j < 8; ++j) {
                    const unsigned short h = f2bf(xv[j]);
                    xh[mi][kk][j] = (short)h;
                    xl[mi][kk][j] = (short)f2bf(xv[j] - bf2f(h));
                }
            }
        }

        #pragma unroll
        for (int cb = 0; cb < 4; ++cb) {
            short8 ah[2], al[2];
            #pragma unroll
            for (int kk = 0; kk < 2; ++kk) {
                const int off = (cb * 16 + m16) * WPAD + kk * 32 + quad * 8;
                ah[kk] = *(const short8*)&Wvh[off];
                al[kk] = *(const short8*)&Wvl[off];
            }
            float bvv[4];
            #pragma unroll
            for (int r = 0; r < 4; ++r) bvv[r] = bv[cb * 16 + quad * 4 + r];
            #pragma unroll
            for (int mi = 0; mi < 4; ++mi) {
                floatx4 d = {0.f, 0.f, 0.f, 0.f};
                #pragma unroll
                for (int kk = 0; kk < 2; ++kk) {
                    d = __builtin_amdgcn_mfma_f32_16x16x32_bf16(ah[kk], xh[mi][kk], d, 0, 0, 0);
                    d = __builtin_amdgcn_mfma_f32_16x16x32_bf16(ah[kk], xl[mi][kk], d, 0, 0, 0);
                    d = __builtin_amdgcn_mfma_f32_16x16x32_bf16(al[kk], xh[mi][kk], d, 0, 0, 0);
                }
                const int im = 4 * wv + mi;
                #pragma unroll
                for (int r = 0; r < 4; ++r)
                    sV[im * VIS + (cb * 16 + quad * 4 + r) * VCS + pxl] = f2bf(d[r] + bvv[r]);
            }
        }
        __syncthreads();

        float acc2[4][16];
        #pragma unroll
        for (int jj = 0; jj < 4; ++jj)
            #pragma unroll
            for (int pp = 0; pp < 16; ++pp) acc2[jj][pp] = 0.f;

        #pragma unroll 4
        for (int i2 = 0; i2 < 16; ++i2) {
            const float4 w4 = *(const float4*)&wts[(((size_t)b * C_ + c) * E_ + i2) * E_ + 4 * q];
            const unsigned short* vp = &sV[i2 * VIS + c * VCS];
            float vvv[16];
            #pragma unroll
            for (int pq = 0; pq < 4; ++pq) {
                const uint2 u = *(const uint2*)(vp + 4 * pq);
                vvv[4 * pq + 0] = __uint_as_float(u.x << 16);
                vvv[4 * pq + 1] = __uint_as_float(u.x & 0xffff0000u);
                vvv[4 * pq + 2] = __uint_as_float(u.y << 16);
                vvv[4 * pq + 3] = __uint_as_float(u.y & 0xffff0000u);
            }
            const float wj0 = w4.x, wj1 = w4.y, wj2 = w4.z, wj3 = w4.w;
            #pragma unroll
            for (int pp = 0; pp < 16; ++pp) {
                acc2[0][pp] = __fmaf_rn(wj0, vvv[pp], acc2[0][pp]);
                acc2[1][pp] = __fmaf_rn(wj1, vvv[pp], acc2[1][pp]);
                acc2[2][pp] = __fmaf_rn(wj2, vvv[pp], acc2[2][pp]);
                acc2[3][pp] = __fmaf_rn(wj3, vvv[pp], acc2[3][pp]);
            }
        }

        #pragma unroll
        for (int jj = 0; jj < 4; ++jj) {
            const int j = 4 * q + jj;
            float* op = out + ((size_t)((b * E_ + j) * C_ + c)) * HW_ + p0;
            #pragma unroll
            for (int pq = 0; pq < 4; ++pq) {
                float4 o;
                o.x = selu_f(acc2[jj][4 * pq + 0]);
                o.y = selu_f(acc2[jj][4 * pq + 1]);
                o.z = selu_f(acc2[jj][4 * pq + 2]);
                o.w = selu_f(acc2[jj][4 * pq + 3]);
                *(float4*)(op + 4 * pq) = o;
            }
        }
        __syncthreads();
    }
}

extern "C" void kernel_launch(void* const* d_in, const int* in_sizes, int n_in,
                              void* d_out, int out_size, void* d_ws, size_t ws_size,
                              hipStream_t stream)
{
    (void)in_sizes; (void)n_in; (void)out_size;
    const float* x  = (const float*)d_in[0];
    const float* Wv = (const float*)d_in[1];
    const float* bv = (const float*)d_in[2];
    const float* Wk = (const float*)d_in[3];
    const float* bk = (const float*)d_in[4];
    const float* Wq = (const float*)d_in[5];
    const float* bq = (const float*)d_in[6];
    float* out = (float*)d_out;

    const size_t wts_b  = (size_t)B_ * C_ * E_ * E_ * sizeof(float);        // 0.5 MB
    const size_t part_b = (size_t)512 * C_ * E_ * E_ * sizeof(float);       // 33.5 MB
    const size_t v_b    = (size_t)B_ * E_ * C_ * HW_ * sizeof(unsigned short); // 67.1 MB

    float* wts = (float*)d_ws;
    float* part = nullptr;
    unsigned short* vbuf = nullptr;
    int use_atomic, have_v;

    if (ws_size >= wts_b + part_b + v_b) {
        use_atomic = 0; have_v = 1;
        part = (float*)((char*)d_ws + wts_b);
        vbuf = (unsigned short*)((char*)d_ws + wts_b + part_b);
    } else if (ws_size >= wts_b + part_b) {
        use_atomic = 0; have_v = 0;
        part = (float*)((char*)d_ws + wts_b);
    } else if (ws_size >= wts_b + v_b) {
        use_atomic = 1; have_v = 1;
        vbuf = (unsigned short*)((char*)d_ws + wts_b);
    } else {
        use_atomic = 1; have_v = 0;
    }

    if (use_atomic)
        hipMemsetAsync(d_ws, 0, wts_b, stream);

    dots_kernel<<<dim3(512), dim3(256), 0, stream>>>(x, Wk, bk, Wq, bq, Wv, bv,
                                                     vbuf, wts, part, use_atomic);
    if (!use_atomic)
        reduce_kernel<<<dim3(128), dim3(256), 0, stream>>>(part, wts);
    softmax_kernel<<<dim3(32), dim3(256), 0, stream>>>(wts);
    if (have_v)
        combine_kernel<<<dim3(512), dim3(256), 0, stream>>>(vbuf, wts, out);
    else
        out_kernel<<<dim3(1024), dim3(256), 0, stream>>>(x, Wv, bv, wts, out);
}

// Round 2
// 508.319 us; speedup vs baseline: 1.0251x; 1.0251x over previous
//
#include <hip/hip_runtime.h>
#include <cstdint>
#include <cstddef>

#define B_   8
#define E_   16
#define CIN_ 64
#define C_   64
#define HW_  4096

typedef __attribute__((ext_vector_type(8))) short short8;
typedef __attribute__((ext_vector_type(4))) float floatx4;

// selu(x) = scale*x (x>0) ; scale*alpha*(exp(x)-1) (x<=0)
__device__ __forceinline__ float selu_f(float v) {
    const float kAlphaScale = 1.7580993408473766f;  // alpha*scale
    const float kScale      = 1.0507009873554805f;
    return v > 0.0f ? kScale * v : kAlphaScale * (__expf(v) - 1.0f);
}

__device__ __forceinline__ unsigned short f2bf(float f) {
    unsigned int u = __float_as_uint(f);
    u += 0x7fffu + ((u >> 16) & 1u);   // RNE
    return (unsigned short)(u >> 16);
}
__device__ __forceinline__ float bf2f(unsigned short h) {
    return __uint_as_float(((unsigned int)h) << 16);
}

// ---------- W staging, XOR-swizzled [64][64] bf16 (no pad; k ^= (row&7)<<3) ----------
__device__ __forceinline__ void stage_w_sw(const float* __restrict__ W,
                                           unsigned short* Wh, unsigned short* Wl, int t) {
    for (int idx = t; idx < 4096; idx += 256) {
        const int c = idx >> 6, k = idx & 63;
        const int o = c * 64 + (k ^ ((c & 7) << 3));
        const float f = W[idx];
        const unsigned short h = f2bf(f);
        Wh[o] = h;
        Wl[o] = f2bf(f - bf2f(h));
    }
}
__device__ __forceinline__ void stage_w_hi(const float* __restrict__ W,
                                           unsigned short* Wh, int t) {
    for (int idx = t; idx < 4096; idx += 256) {
        const int c = idx >> 6, k = idx & 63;
        Wh[c * 64 + (k ^ ((c & 7) << 3))] = f2bf(W[idx]);
    }
}

// legacy padded staging (fallback out_kernel only)
#define WPAD 72
__device__ __forceinline__ void stage_w(const float* __restrict__ W,
                                        unsigned short* Wh, unsigned short* Wl, int t) {
    for (int idx = t; idx < 4096; idx += 256) {
        const int c = idx >> 6, k = idx & 63;
        const float f = W[idx];
        const unsigned short h = f2bf(f);
        Wh[c * WPAD + k] = h;
        Wl[c * WPAD + k] = f2bf(f - bf2f(h));
    }
}

// ---------------- kernel 1: K/Q conv (MFMA) + gram partials + fused V conv ----------------
// grid 512 (= B*64 px-tiles of 64), block 256 (4 waves).
// V is written to vbuf in a PX-TILED layout: tile T=((b*64+blk)*4+chunk) is a
// contiguous [i=16][c=64][px=16] bf16 block (32 KB). Each wave's store burst for
// (mi,q4) covers a contiguous 512B region -> full L2 lines, no RMW amplification.
#define K1_CH 4
#define KCS 18    // sK c-stride (16 px padded to 18)
#define KIS 292   // sK member-stride (16*18+4)

__global__ __launch_bounds__(256, 2)
void dots_kernel(const float* __restrict__ x,
                 const float* __restrict__ Wk, const float* __restrict__ bk,
                 const float* __restrict__ Wq, const float* __restrict__ bq,
                 const float* __restrict__ Wv, const float* __restrict__ bv,
                 unsigned short* __restrict__ vbuf,   // may be null (no V fusion)
                 float* __restrict__ wts, float* __restrict__ part,
                 int use_atomic)
{
    __shared__ float sK[E_ * KIS];
    __shared__ float sQ[E_ * KIS];
    __shared__ __align__(16) unsigned short Wkh[4096], Wkl[4096];
    __shared__ __align__(16) unsigned short Wqh[4096], Wql[4096];
    __shared__ __align__(16) unsigned short Wvh[4096];

    const int t    = threadIdx.x;
    const int b    = blockIdx.x >> 6;
    const int blk  = blockIdx.x & 63;
    const int wv   = t >> 6;          // wave id: members 4wv..4wv+3
    const int lane = t & 63;
    const int quad = lane >> 4;
    const int pxl  = lane & 15;       // B-frag n / D col
    const int m16  = lane & 15;       // A-frag m
    // gram mapping (block-wide)
    const int gc = t >> 4;            // channel-in-quarter
    const int s  = t & 15;
    const int ib = (s >> 2) << 2;
    const int jb = (s & 3) << 2;

    stage_w_sw(Wk, Wkh, Wkl, t);
    stage_w_sw(Wq, Wqh, Wql, t);
    if (vbuf) stage_w_hi(Wv, Wvh, t);

    float acc[4][4][4];
    #pragma unroll
    for (int a0 = 0; a0 < 4; ++a0)
      #pragma unroll
      for (int a1 = 0; a1 < 4; ++a1)
        #pragma unroll
        for (int a2 = 0; a2 < 4; ++a2) acc[a0][a1][a2] = 0.0f;

    __syncthreads();   // W staged

    for (int chunk = 0; chunk < K1_CH; ++chunk) {
        const int p0 = blk * (16 * K1_CH) + chunk * 16;
        const size_t tb = ((size_t)((b * 64 + blk) * 4 + chunk)) * 16384;  // V tile base

        // x B-frags: lane holds x[cin=kk*32+quad*8+j][px=p0+pxl], hi/lo bf16
        short8 xh[4][2], xl[4][2];
        #pragma unroll
        for (int mi = 0; mi < 4; ++mi) {
            const int im = 4 * wv + mi;
            const float* xg = x + ((size_t)(b * E_ + im) * CIN_) * HW_ + p0 + pxl;
            #pragma unroll
            for (int kk = 0; kk < 2; ++kk) {
                float xv[8];
                #pragma unroll
                for (int j = 0; j < 8; ++j)
                    xv[j] = xg[(size_t)(kk * 32 + quad * 8 + j) * HW_];
                #pragma unroll
                for (int j = 0; j < 8; ++j) {
                    const unsigned short h = f2bf(xv[j]);
                    xh[mi][kk][j] = (short)h;
                    xl[mi][kk][j] = (short)f2bf(xv[j] - bf2f(h));
                }
            }
        }

        for (int q4 = 0; q4 < 4; ++q4) {
            const int row = q4 * 16 + m16;
            const int ksw = (row & 7) << 3;

            // ---- V conv first (global stores issue early, hidden under K/Q conv) ----
            if (vbuf) {
                short8 vh[2];
                #pragma unroll
                for (int kk = 0; kk < 2; ++kk) {
                    const int k0 = kk * 32 + quad * 8;
                    vh[kk] = *(const short8*)&Wvh[row * 64 + (k0 ^ ksw)];
                }
                float bvv[4];
                #pragma unroll
                for (int r = 0; r < 4; ++r) bvv[r] = bv[q4 * 16 + quad * 4 + r];
                #pragma unroll
                for (int mi = 0; mi < 4; ++mi) {
                    floatx4 d = {0.f, 0.f, 0.f, 0.f};
                    d = __builtin_amdgcn_mfma_f32_16x16x32_bf16(vh[0], xh[mi][0], d, 0, 0, 0);
                    d = __builtin_amdgcn_mfma_f32_16x16x32_bf16(vh[0], xl[mi][0], d, 0, 0, 0);
                    d = __builtin_amdgcn_mfma_f32_16x16x32_bf16(vh[1], xh[mi][1], d, 0, 0, 0);
                    d = __builtin_amdgcn_mfma_f32_16x16x32_bf16(vh[1], xl[mi][1], d, 0, 0, 0);
                    const int im = 4 * wv + mi;
                    #pragma unroll
                    for (int r = 0; r < 4; ++r)
                        vbuf[tb + im * 1024 + (q4 * 16 + quad * 4 + r) * 16 + pxl]
                            = f2bf(d[r] + bvv[r]);
                }
            }

            // ---- K conv for this channel quarter ----
            {
                short8 ah[2], al[2];
                #pragma unroll
                for (int kk = 0; kk < 2; ++kk) {
                    const int k0 = kk * 32 + quad * 8;
                    const int off = row * 64 + (k0 ^ ksw);
                    ah[kk] = *(const short8*)&Wkh[off];
                    al[kk] = *(const short8*)&Wkl[off];
                }
                float bkv[4];
                #pragma unroll
                for (int r = 0; r < 4; ++r) bkv[r] = bk[q4 * 16 + quad * 4 + r];
                #pragma unroll
                for (int mi = 0; mi < 4; ++mi) {
                    floatx4 d = {0.f, 0.f, 0.f, 0.f};
                    #pragma unroll
                    for (int kk = 0; kk < 2; ++kk) {
                        d = __builtin_amdgcn_mfma_f32_16x16x32_bf16(ah[kk], xh[mi][kk], d, 0, 0, 0);
                        d = __builtin_amdgcn_mfma_f32_16x16x32_bf16(ah[kk], xl[mi][kk], d, 0, 0, 0);
                        d = __builtin_amdgcn_mfma_f32_16x16x32_bf16(al[kk], xh[mi][kk], d, 0, 0, 0);
                    }
                    const int im = 4 * wv + mi;
                    #pragma unroll
                    for (int r = 0; r < 4; ++r)
                        sK[im * KIS + (quad * 4 + r) * KCS + pxl] = selu_f(d[r] + bkv[r]);
                }
            }
            // ---- Q conv for this channel quarter ----
            {
                short8 ah[2], al[2];
                #pragma unroll
                for (int kk = 0; kk < 2; ++kk) {
                    const int k0 = kk * 32 + quad * 8;
                    const int off = row * 64 + (k0 ^ ksw);
                    ah[kk] = *(const short8*)&Wqh[off];
                    al[kk] = *(const short8*)&Wql[off];
                }
                float bqv[4];
                #pragma unroll
                for (int r = 0; r < 4; ++r) bqv[r] = bq[q4 * 16 + quad * 4 + r];
                #pragma unroll
                for (int mi = 0; mi < 4; ++mi) {
                    floatx4 d = {0.f, 0.f, 0.f, 0.f};
                    #pragma unroll
                    for (int kk = 0; kk < 2; ++kk) {
                        d = __builtin_amdgcn_mfma_f32_16x16x32_bf16(ah[kk], xh[mi][kk], d, 0, 0, 0);
                        d = __builtin_amdgcn_mfma_f32_16x16x32_bf16(ah[kk], xl[mi][kk], d, 0, 0, 0);
                        d = __builtin_amdgcn_mfma_f32_16x16x32_bf16(al[kk], xh[mi][kk], d, 0, 0, 0);
                    }
                    const int im = 4 * wv + mi;
                    #pragma unroll
                    for (int r = 0; r < 4; ++r)
                        sQ[im * KIS + (quad * 4 + r) * KCS + pxl] = selu_f(d[r] + bqv[r]);
                }
            }
            __syncthreads();
            // ---- gram: dots[c=q4*16+gc][i=ib+u][j=jb+v] += K_i*Q_j over 16 px ----
            #pragma unroll
            for (int p2 = 0; p2 < 8; ++p2) {
                float2 kv[4], qv[4];
                #pragma unroll
                for (int u = 0; u < 4; ++u)
                    kv[u] = *(const float2*)&sK[(ib + u) * KIS + gc * KCS + 2 * p2];
                #pragma unroll
                for (int v = 0; v < 4; ++v)
                    qv[v] = *(const float2*)&sQ[(jb + v) * KIS + gc * KCS + 2 * p2];
                #pragma unroll
                for (int u = 0; u < 4; ++u)
                    #pragma unroll
                    for (int v = 0; v < 4; ++v)
                        acc[q4][u][v] = __fmaf_rn(kv[u].y, qv[v].y,
                                         __fmaf_rn(kv[u].x, qv[v].x, acc[q4][u][v]));
            }
            __syncthreads();
        }
    }

    if (use_atomic) {
        #pragma unroll
        for (int q4 = 0; q4 < 4; ++q4)
          #pragma unroll
          for (int u = 0; u < 4; ++u)
            #pragma unroll
            for (int v = 0; v < 4; ++v)
              atomicAdd(&wts[(((size_t)b * C_ + (q4 * 16 + gc)) * E_ + (ib + u)) * E_ + (jb + v)],
                        acc[q4][u][v]);
    } else {
        float* pb = part + (size_t)blockIdx.x * (C_ * E_ * E_);
        #pragma unroll
        for (int q4 = 0; q4 < 4; ++q4) {
            __syncthreads();
            #pragma unroll
            for (int u = 0; u < 4; ++u)
              #pragma unroll
              for (int v = 0; v < 4; ++v)
                sK[gc * 256 + (ib + u) * 16 + (jb + v)] = acc[q4][u][v];
            __syncthreads();
            for (int e = t; e < 4096; e += 256)
                pb[q4 * 4096 + e] = sK[e];
        }
    }
}

// ---------------- kernel 2a: reduce partials ----------------
__global__ __launch_bounds__(256)
void reduce_kernel(const float* __restrict__ part, float* __restrict__ wts)
{
    const int tid = blockIdx.x * 256 + threadIdx.x;  // 0..32767 float4 slots
    const int b   = tid >> 12;
    const int off = tid & 4095;
    float4 sum = make_float4(0.f, 0.f, 0.f, 0.f);
    const float* base = part + (size_t)b * 64 * 16384;
    #pragma unroll 8
    for (int blk = 0; blk < 64; ++blk) {
        float4 v = *(const float4*)(base + (size_t)blk * 16384 + off * 4);
        sum.x += v.x; sum.y += v.y; sum.z += v.z; sum.w += v.w;
    }
    *(float4*)(wts + (size_t)b * 16384 + off * 4) = sum;
}

// ---------------- kernel 2b: softmax over i ----------------
__global__ __launch_bounds__(256)
void softmax_kernel(float* __restrict__ wts)
{
    const int tid = blockIdx.x * 256 + threadIdx.x;  // 8192 = B*C*E(j)
    const int j   = tid & 15;
    const int bc  = tid >> 4;
    float* base = wts + (size_t)bc * 256 + j;
    float v[16];
    #pragma unroll
    for (int i = 0; i < 16; ++i) v[i] = base[i * 16];
    float m = v[0];
    #pragma unroll
    for (int i = 1; i < 16; ++i) m = fmaxf(m, v[i]);
    float sum = 0.f;
    #pragma unroll
    for (int i = 0; i < 16; ++i) { v[i] = __expf(v[i] - m); sum += v[i]; }
    const float r = 1.0f / sum;
    #pragma unroll
    for (int i = 0; i < 16; ++i) base[i * 16] = v[i] * r;
}

// ---------------- kernel 3 (fused path): streaming combine from tiled V ----------------
// grid 512 (= B*64 tiles of 64 px), block 256, 2 chunks of 32 px.
// Reads vbuf tiles sequentially (16B coalesced); each thread owns (c, q) and
// writes 4 j-rows x 32 px = full 128B lines. out = selu(sum_i w[b,c,i,j]*V[b,i,c,p]).
#define VCS2 36                 // sV c-stride (ushort; 32 px + 4 pad; mult of 4)
#define SVIS (64 * VCS2)        // member stride = 2304

__global__ __launch_bounds__(256, 2)
void combine_kernel(const unsigned short* __restrict__ vbuf,
                    const float* __restrict__ wts, float* __restrict__ out)
{
    __shared__ __align__(16) unsigned short sV[E_ * SVIS];   // 73728 B

    const int t   = threadIdx.x;
    const int b   = blockIdx.x >> 6;
    const int blk = blockIdx.x & 63;
    const int c   = t >> 2;     // channel
    const int q   = t & 3;      // j-quad

    const size_t tbase = ((size_t)(b * 64 + blk)) * 4 * 16384;

    for (int u = 0; u < 2; ++u) {
        const int p0 = blk * 64 + u * 32;

        if (u) __syncthreads();    // previous chunk's sV reads complete
        // stage 2 tiles (32 px): 16i x 64c x 32px bf16 = 64 KB, fully coalesced
        #pragma unroll 4
        for (int it = 0; it < 16; ++it) {
            const int idx = t + 256 * it;
            const int g   = idx & 3;            // 8-px group: px g*8..g*8+7
            const int cc  = (idx >> 2) & 63;
            const int i   = idx >> 8;
            const unsigned short* src = vbuf + tbase
                + (size_t)(2 * u + (g >> 1)) * 16384 + i * 1024 + cc * 16 + (g & 1) * 8;
            const uint4 v = *(const uint4*)src;
            unsigned short* dst = &sV[i * SVIS + cc * VCS2 + g * 8];
            *(uint2*)(dst)     = make_uint2(v.x, v.y);
            *(uint2*)(dst + 4) = make_uint2(v.z, v.w);
        }
        __syncthreads();

        float acc2[4][32];
        #pragma unroll
        for (int jj = 0; jj < 4; ++jj)
            #pragma unroll
            for (int pp = 0; pp < 32; ++pp) acc2[jj][pp] = 0.f;

        #pragma unroll 4
        for (int i2 = 0; i2 < 16; ++i2) {
            const float4 w4 = *(const float4*)&wts[(((size_t)b * C_ + c) * E_ + i2) * E_ + 4 * q];
            const unsigned short* vp = &sV[i2 * SVIS + c * VCS2];
            const float wj0 = w4.x, wj1 = w4.y, wj2 = w4.z, wj3 = w4.w;
            #pragma unroll
            for (int pq8 = 0; pq8 < 4; ++pq8) {
                const uint2 ua = *(const uint2*)(vp + 8 * pq8);
                const uint2 ub = *(const uint2*)(vp + 8 * pq8 + 4);
                float vv[8];
                vv[0] = __uint_as_float(ua.x << 16);
                vv[1] = __uint_as_float(ua.x & 0xffff0000u);
                vv[2] = __uint_as_float(ua.y << 16);
                vv[3] = __uint_as_float(ua.y & 0xffff0000u);
                vv[4] = __uint_as_float(ub.x << 16);
                vv[5] = __uint_as_float(ub.x & 0xffff0000u);
                vv[6] = __uint_as_float(ub.y << 16);
                vv[7] = __uint_as_float(ub.y & 0xffff0000u);
                #pragma unroll
                for (int k = 0; k < 8; ++k) {
                    const int pp = 8 * pq8 + k;
                    acc2[0][pp] = __fmaf_rn(wj0, vv[k], acc2[0][pp]);
                    acc2[1][pp] = __fmaf_rn(wj1, vv[k], acc2[1][pp]);
                    acc2[2][pp] = __fmaf_rn(wj2, vv[k], acc2[2][pp]);
                    acc2[3][pp] = __fmaf_rn(wj3, vv[k], acc2[3][pp]);
                }
            }
        }

        #pragma unroll
        for (int jj = 0; jj < 4; ++jj) {
            const int j = 4 * q + jj;
            float* op = out + ((size_t)((b * E_ + j) * C_ + c)) * HW_ + p0;
            #pragma unroll
            for (int s4 = 0; s4 < 8; ++s4) {
                float4 o;
                o.x = selu_f(acc2[jj][4 * s4 + 0]);
                o.y = selu_f(acc2[jj][4 * s4 + 1]);
                o.z = selu_f(acc2[jj][4 * s4 + 2]);
                o.w = selu_f(acc2[jj][4 * s4 + 3]);
                *(float4*)(op + 4 * s4) = o;
            }
        }
    }
}

// ---------------- kernel 3 (fallback): V conv (MFMA) + combine + selu ----------------
// Used only when workspace can't hold the V buffer. Unchanged verified code.
#define K3_CH 2
#define VCS 20
#define VIS 1284

__global__ __launch_bounds__(256, 2)
void out_kernel(const float* __restrict__ x,
                const float* __restrict__ Wv, const float* __restrict__ bv,
                const float* __restrict__ wts, float* __restrict__ out)
{
    __shared__ __align__(16) unsigned short sV[E_ * VIS];   // V staged bf16
    __shared__ __align__(16) unsigned short Wvh[64 * WPAD], Wvl[64 * WPAD];

    const int t    = threadIdx.x;
    const int b    = blockIdx.x >> 7;
    const int blk  = blockIdx.x & 127;
    const int wv   = t >> 6;
    const int lane = t & 63;
    const int quad = lane >> 4;
    const int pxl  = lane & 15;
    const int m16  = lane & 15;
    const int c    = t >> 2;     // combine: channel
    const int q    = t & 3;      // combine: j-quad

    stage_w(Wv, Wvh, Wvl, t);
    __syncthreads();

    for (int chunk = 0; chunk < K3_CH; ++chunk) {
        const int p0 = blk * (16 * K3_CH) + chunk * 16;

        short8 xh[4][2], xl[4][2];
        #pragma unroll
        for (int mi = 0; mi < 4; ++mi) {
            const int im = 4 * wv + mi;
            const float* xg = x + ((size_t)(b * E_ + im) * CIN_) * HW_ + p0 + pxl;
            #pragma unroll
            for (int kk = 0; kk < 2; ++kk) {
                float xv[8];
                #pragma unroll
                for (int j = 0; j < 8; ++j)
                    xv[j] = xg[(size_t)(kk * 32 + quad * 8 + j) * HW_];
                #pragma unroll
                for (int j = 0; j < 8; ++j) {
                    const unsigned short h = f2bf(xv[j]);
                    xh[mi][kk][j] = (short)h;
                    xl[mi][kk][j] = (short)f2bf(xv[j] - bf2f(h));
                }
            }
        }

        #pragma unroll
        for (int cb = 0; cb < 4; ++cb) {
            short8 ah[2], al[2];
            #pragma unroll
            for (int kk = 0; kk < 2; ++kk) {
                const int off = (cb * 16 + m16) * WPAD + kk * 32 + quad * 8;
                ah[kk] = *(const short8*)&Wvh[off];
                al[kk] = *(const short8*)&Wvl[off];
            }
            float bvv[4];
            #pragma unroll
            for (int r = 0; r < 4; ++r) bvv[r] = bv[cb * 16 + quad * 4 + r];
            #pragma unroll
            for (int mi = 0; mi < 4; ++mi) {
                floatx4 d = {0.f, 0.f, 0.f, 0.f};
                #pragma unroll
                for (int kk = 0; kk < 2; ++kk) {
                    d = __builtin_amdgcn_mfma_f32_16x16x32_bf16(ah[kk], xh[mi][kk], d, 0, 0, 0);
                    d = __builtin_amdgcn_mfma_f32_16x16x32_bf16(ah[kk], xl[mi][kk], d, 0, 0, 0);
                    d = __builtin_amdgcn_mfma_f32_16x16x32_bf16(al[kk], xh[mi][kk], d, 0, 0, 0);
                }
                const int im = 4 * wv + mi;
                #pragma unroll
                for (int r = 0; r < 4; ++r)
                    sV[im * VIS + (cb * 16 + quad * 4 + r) * VCS + pxl] = f2bf(d[r] + bvv[r]);
            }
        }
        __syncthreads();

        float acc2[4][16];
        #pragma unroll
        for (int jj = 0; jj < 4; ++jj)
            #pragma unroll
            for (int pp = 0; pp < 16; ++pp) acc2[jj][pp] = 0.f;

        #pragma unroll 4
        for (int i2 = 0; i2 < 16; ++i2) {
            const float4 w4 = *(const float4*)&wts[(((size_t)b * C_ + c) * E_ + i2) * E_ + 4 * q];
            const unsigned short* vp = &sV[i2 * VIS + c * VCS];
            float vvv[16];
            #pragma unroll
            for (int pq = 0; pq < 4; ++pq) {
                const uint2 u = *(const uint2*)(vp + 4 * pq);
                vvv[4 * pq + 0] = __uint_as_float(u.x << 16);
                vvv[4 * pq + 1] = __uint_as_float(u.x & 0xffff0000u);
                vvv[4 * pq + 2] = __uint_as_float(u.y << 16);
                vvv[4 * pq + 3] = __uint_as_float(u.y & 0xffff0000u);
            }
            const float wj0 = w4.x, wj1 = w4.y, wj2 = w4.z, wj3 = w4.w;
            #pragma unroll
            for (int pp = 0; pp < 16; ++pp) {
                acc2[0][pp] = __fmaf_rn(wj0, vvv[pp], acc2[0][pp]);
                acc2[1][pp] = __fmaf_rn(wj1, vvv[pp], acc2[1][pp]);
                acc2[2][pp] = __fmaf_rn(wj2, vvv[pp], acc2[2][pp]);
                acc2[3][pp] = __fmaf_rn(wj3, vvv[pp], acc2[3][pp]);
            }
        }

        #pragma unroll
        for (int jj = 0; jj < 4; ++jj) {
            const int j = 4 * q + jj;
            float* op = out + ((size_t)((b * E_ + j) * C_ + c)) * HW_ + p0;
            #pragma unroll
            for (int pq = 0; pq < 4; ++pq) {
                float4 o;
                o.x = selu_f(acc2[jj][4 * pq + 0]);
                o.y = selu_f(acc2[jj][4 * pq + 1]);
                o.z = selu_f(acc2[jj][4 * pq + 2]);
                o.w = selu_f(acc2[jj][4 * pq + 3]);
                *(float4*)(op + 4 * pq) = o;
            }
        }
        __syncthreads();
    }
}

extern "C" void kernel_launch(void* const* d_in, const int* in_sizes, int n_in,
                              void* d_out, int out_size, void* d_ws, size_t ws_size,
                              hipStream_t stream)
{
    (void)in_sizes; (void)n_in; (void)out_size;
    const float* x  = (const float*)d_in[0];
    const float* Wv = (const float*)d_in[1];
    const float* bv = (const float*)d_in[2];
    const float* Wk = (const float*)d_in[3];
    const float* bk = (const float*)d_in[4];
    const float* Wq = (const float*)d_in[5];
    const float* bq = (const float*)d_in[6];
    float* out = (float*)d_out;

    const size_t wts_b  = (size_t)B_ * C_ * E_ * E_ * sizeof(float);        // 0.5 MB
    const size_t part_b = (size_t)512 * C_ * E_ * E_ * sizeof(float);       // 33.5 MB
    const size_t v_b    = (size_t)B_ * E_ * C_ * HW_ * sizeof(unsigned short); // 67.1 MB

    float* wts = (float*)d_ws;
    float* part = nullptr;
    unsigned short* vbuf = nullptr;
    int use_atomic, have_v;

    if (ws_size >= wts_b + part_b + v_b) {
        use_atomic = 0; have_v = 1;
        part = (float*)((char*)d_ws + wts_b);
        vbuf = (unsigned short*)((char*)d_ws + wts_b + part_b);
    } else if (ws_size >= wts_b + part_b) {
        use_atomic = 0; have_v = 0;
        part = (float*)((char*)d_ws + wts_b);
    } else if (ws_size >= wts_b + v_b) {
        use_atomic = 1; have_v = 1;
        vbuf = (unsigned short*)((char*)d_ws + wts_b);
    } else {
        use_atomic = 1; have_v = 0;
    }

    if (use_atomic)
        hipMemsetAsync(d_ws, 0, wts_b, stream);

    dots_kernel<<<dim3(512), dim3(256), 0, stream>>>(x, Wk, bk, Wq, bq, Wv, bv,
                                                     vbuf, wts, part, use_atomic);
    if (!use_atomic)
        reduce_kernel<<<dim3(128), dim3(256), 0, stream>>>(part, wts);
    softmax_kernel<<<dim3(32), dim3(256), 0, stream>>>(wts);
    if (have_v)
        combine_kernel<<<dim3(512), dim3(256), 0, stream>>>(vbuf, wts, out);
    else
        out_kernel<<<dim3(1024), dim3(256), 0, stream>>>(x, Wv, bv, wts, out);
}